// Round 17
// baseline (131.181 us; speedup 1.0000x reference)
//
#include <hip/hip_runtime.h>

// CRS rate-and-state model. R -> et*R/(1+c*R) is a Mobius map [[a,0],[c,1]];
// maps compose associatively -> whole T=4096 row is ONE two-level scan.
// R17 = R16 (125.7us) + TWO ROWS PER BLOCK with row-1 inputs prefetched to
// LDS via global_load_lds. Register prefetch was compiler-defeated 5x
// (R2/R4/R12/R13/R14: loads sunk or regs demoted); global_load_lds is
// side-effecting (writes LDS) and CANNOT be sunk past the memory-clobber
// barriers -> the fetch is issued at the top no matter what, so row-1's
// read round-trip overlaps row-0's entire pipeline.
// Ledger: wave w stages elements [512w,512w+512) of row-1 p/dpdt; thread tid
// reads [8tid,8tid+8) of the SAME wave's chunk -> per-wave vmcnt(4) (not a
// block barrier) suffices; >=4 body stores are always the newest outstanding
// vmem, so wait-to-4 provably retires the 4 staging loads first.
// delta_t row 1 rides as plain register loads (1/3 of read leg exposed).
// LDS 33KB bounce + 32KB stage = 65.1KB -> 2 blocks/CU.
// Keeps all R16 machinery: dual skewed bounce (per-WAVE-INSTRUCTION lane
// contiguity), 64B-aligned nt f4 stores, lgkm-only barriers, log2-telescope.

#define C_TNSR  0.001f
#define C_TSSR  0.002f
#define C_SIGMA 50.0f
#define C_BIOT  0.3f
#define C_R0    0.0001f
#define C_N0    0.0001f
#define LN2F    0.69314718056f

constexpr int B = 8192;
constexpr int T = 4096;
constexpr int STEPS = 8;           // per thread
constexpr int NTHR  = 512;         // threads per block
constexpr int WAVES = NTHR / 64;   // 8

typedef float f4 __attribute__((ext_vector_type(4)));

__device__ __forceinline__ int SIDX(int m) { return m + (m >> 5); }

struct SH {
    float lsR[T + T / 32];   // 16.5 KB bounce (skew-indexed)
    float lsN[T + T / 32];
    float stP[T];            // row-1 p stage (linear: gload_lds needs it)
    float stD[T];            // row-1 dpdt stage
    float sA[WAVES], sC[WAVES], sS[WAVES];
};

// workgroup barrier WITHOUT the compiler's vmcnt(0) drain (LDS ordering only)
__device__ __forceinline__ void barrier_lgkm() {
    asm volatile("s_waitcnt lgkmcnt(0)\n\ts_barrier" ::: "memory");
}

// async global->LDS: each lane writes 16B at ldst + lane*16
__device__ __forceinline__ void gload_lds16(const float* gsrc, float* ldst) {
    __builtin_amdgcn_global_load_lds(
        (const __attribute__((address_space(1))) void*)gsrc,
        (__attribute__((address_space(3))) void*)ldst,
        16, 0, 0);
}

__device__ __forceinline__ void do_row(
    int b, int tid, int lane, int wid,
    float mu, float rc, float rf,
    f4 pv0, f4 pv1, f4 dv0, f4 dv1, f4 tv0, f4 tv1,
    SH& sh, float* __restrict__ Rt, float* __restrict__ Nt)
{
    const float eta = 1.0f / rf;
    const float rcS = rc * C_SIGMA;
    const float rcB = rc * C_BIOT;
    const float sdB = C_TSSR - mu * C_TNSR;
    const float rfln2 = rf * LN2F;
    const int seg = tid * STEPS;

    // ---- phase 1: per-thread inclusive Mobius prefixes ----
    float Aj[STEPS], Cj[STEPS], kln[STEPS];
    float A = 1.0f, C = 0.0f;
#pragma unroll
    for (int j = 0; j < STEPS; ++j) {
        float pp = (j < 4) ? pv0[j] : pv1[j - 4];
        float dd = (j < 4) ? dv0[j] : dv1[j - 4];
        float tt = (j < 4) ? tv0[j] : tv1[j - 4];
        float sd   = fmaf(mu, dd, sdB);
        float asig = fmaf(-rcB, pp, rcS);
        float e    = __expf(__fdividef(sd * tt, asig));
        float c    = __fdividef(eta * (e - 1.0f), sd);
        kln[j] = asig * rfln2;
        C = fmaf(c, A, C);
        A = A * e;
        Aj[j] = A;
        Cj[j] = C;
    }

    // ---- phase 2a: wave-inclusive scan of (A,C) ----
#pragma unroll
    for (int o = 1; o < 64; o <<= 1) {
        float Ap = __shfl_up(A, (unsigned)o, 64);
        float Cp = __shfl_up(C, (unsigned)o, 64);
        if (lane >= o) { C = fmaf(C, Ap, Cp); A = A * Ap; }
    }
    float Ae = __shfl_up(A, 1u, 64);
    float Ce = __shfl_up(C, 1u, 64);
    if (lane == 0) { Ae = 1.0f; Ce = 0.0f; }

    // ---- phase 2b: cross-wave composition via LDS ----
    if (lane == 63) { sh.sA[wid] = A; sh.sC[wid] = C; }
    barrier_lgkm();                                    // bar 1
    float PA = 1.0f, PC = 0.0f;
#pragma unroll
    for (int w = 0; w < WAVES - 1; ++w) {
        if (w < wid) { PC = fmaf(sh.sC[w], PA, PC); PA = sh.sA[w] * PA; }
    }
    float EA = Ae * PA;
    float EC = fmaf(Ce, PA, PC);
    float Rt_ = __fdividef(EA * C_R0, fmaf(EC, C_R0, 1.0f));

    // ---- phase 3: closed-form outputs; N via log2 telescope ----
    float nn[STEPS];
    float ns = 0.0f;
    float lgPrev = 0.0f;
#pragma unroll
    for (int j = 0; j < STEPS; ++j) {
        float L   = fmaf(Cj[j], Rt_, 1.0f);
        float rlj = __fdividef(1.0f, L);
        sh.lsR[SIDX(seg + j)] = (Aj[j] * Rt_) * rlj;
        float lg = __log2f(L);
        ns += kln[j] * (lg - lgPrev);
        nn[j] = ns;
        lgPrev = lg;
    }

    // ---- phase 4a: wave prefix sum of per-thread N totals ----
    float S = ns;
#pragma unroll
    for (int o = 1; o < 64; o <<= 1) {
        float Sp = __shfl_up(S, (unsigned)o, 64);
        if (lane >= o) S += Sp;
    }
    if (lane == 63) sh.sS[wid] = S;
    barrier_lgkm();                                    // bar 2: lsR + sS ready

    // ---- store-stage geometry ----
    const size_t g0 = (size_t)b * (T + 1) + 1;
    const int s  = (int)((16 - (g0 & 15)) & 15);
    const int tl = (T - s) & 3;
    const int bodyEnd = T - tl;

    // ---- R store stage FIRST (VMEM pipe; overlaps N work below) ----
    if (tid == 0) {
        __builtin_nontemporal_store(C_R0, Rt + g0 - 1);
        __builtin_nontemporal_store(C_N0, Nt + g0 - 1);
    }
    if (tid < s)  __builtin_nontemporal_store(sh.lsR[SIDX(tid)], Rt + g0 + tid);
    if (tid < tl) { int m = bodyEnd + tid;
                    __builtin_nontemporal_store(sh.lsR[SIDX(m)], Rt + g0 + m); }
#pragma unroll
    for (int q = 0; q < 2; ++q) {
        int m0 = s + q * 2048 + tid * 4;
        if (m0 + 4 <= bodyEnd) {
            f4 r;
#pragma unroll
            for (int c = 0; c < 4; ++c) r[c] = sh.lsR[SIDX(m0 + c)];
            __builtin_nontemporal_store(r, (f4*)(Rt + g0 + m0));
        }
    }

    // ---- phase 4b: cross-wave N base + bounce N (DS pipe, concurrent) ----
    float PS = C_N0;
#pragma unroll
    for (int w = 0; w < WAVES - 1; ++w) {
        if (w < wid) PS += sh.sS[w];
    }
    float base = PS + (S - ns);
#pragma unroll
    for (int j = 0; j < STEPS; ++j)
        sh.lsN[SIDX(seg + j)] = base + nn[j];

    barrier_lgkm();                                    // bar 3: N in LDS

    // ---- N store stage ----
    if (tid < s)  __builtin_nontemporal_store(sh.lsN[SIDX(tid)], Nt + g0 + tid);
    if (tid < tl) { int m = bodyEnd + tid;
                    __builtin_nontemporal_store(sh.lsN[SIDX(m)], Nt + g0 + m); }
#pragma unroll
    for (int q = 0; q < 2; ++q) {
        int m0 = s + q * 2048 + tid * 4;
        if (m0 + 4 <= bodyEnd) {
            f4 n;
#pragma unroll
            for (int c = 0; c < 4; ++c) n[c] = sh.lsN[SIDX(m0 + c)];
            __builtin_nontemporal_store(n, (f4*)(Nt + g0 + m0));
        }
    }
}

__global__ __launch_bounds__(NTHR, 4)
void crs_pair_kernel(const float* __restrict__ params,
                     const float* __restrict__ p,
                     const float* __restrict__ dpdt,
                     const float* __restrict__ dtv,
                     float* __restrict__ Rt,
                     float* __restrict__ Nt)
{
    __shared__ SH sh;

    const int tid  = threadIdx.x;
    const int lane = tid & 63;
    const int wid  = tid >> 6;
    const int b0   = blockIdx.x * 2;
    const int b1   = b0 + 1;

    const float mu0 = params[b0 * 3 + 0];
    const float rc0 = params[b0 * 3 + 1];
    const float rf0 = params[b0 * 3 + 2];
    const float mu1 = params[b1 * 3 + 0];
    const float rc1 = params[b1 * 3 + 1];
    const float rf1 = params[b1 * 3 + 2];

    const int seg = tid * STEPS;

    // ---- row 0 inputs: plain register loads (needed immediately) ----
    const float* pr0 = p    + (size_t)b0 * T + seg;
    const float* dr0 = dpdt + (size_t)b0 * T + seg;
    const float* tr0 = dtv  + (size_t)b0 * T + seg;
    f4 a_pv0 = *(const f4*)(pr0);
    f4 a_pv1 = *(const f4*)(pr0 + 4);
    f4 a_dv0 = *(const f4*)(dr0);
    f4 a_dv1 = *(const f4*)(dr0 + 4);
    f4 a_tv0 = *(const f4*)(tr0);
    f4 a_tv1 = *(const f4*)(tr0 + 4);

    // ---- row 1 delta_t: plain loads (compiler may sink; 1/3 of leg) ----
    const float* tr1 = dtv + (size_t)b1 * T + seg;
    f4 b_tv0 = *(const f4*)(tr1);
    f4 b_tv1 = *(const f4*)(tr1 + 4);

    // ---- row 1 p/dpdt: async stage to LDS (CANNOT be sunk) ----
    // wave w stages elements [512w, 512w+512): 2 x 1KB chunks per stream.
    {
        const int cb = wid * 512;
        const float* gp = p    + (size_t)b1 * T + cb + lane * 4;
        const float* gd = dpdt + (size_t)b1 * T + cb + lane * 4;
        gload_lds16(gp,       &sh.stP[cb]);
        gload_lds16(gp + 256, &sh.stP[cb + 256]);
        gload_lds16(gd,       &sh.stD[cb]);
        gload_lds16(gd + 256, &sh.stD[cb + 256]);
    }

    // ---- row 0: full pipeline (row-1 fetches in flight underneath) ----
    do_row(b0, tid, lane, wid, mu0, rc0, rf0,
           a_pv0, a_pv1, a_dv0, a_dv1, a_tv0, a_tv1, sh, Rt, Nt);

    // ---- retire the 4 staging loads: >=4 body stores are newest, so
    //      wait-to-4 provably drains the (older) gloads. Per-wave: each
    //      thread reads only its own wave's staged chunk -> no barrier. ----
    asm volatile("s_waitcnt vmcnt(4)" ::: "memory");
    __builtin_amdgcn_sched_barrier(0);

    // ---- row 1 inputs from LDS stage ----
    f4 c_pv0 = *(const f4*)(sh.stP + seg);
    f4 c_pv1 = *(const f4*)(sh.stP + seg + 4);
    f4 c_dv0 = *(const f4*)(sh.stD + seg);
    f4 c_dv1 = *(const f4*)(sh.stD + seg + 4);

    do_row(b1, tid, lane, wid, mu1, rc1, rf1,
           c_pv0, c_pv1, c_dv0, c_dv1, b_tv0, b_tv1, sh, Rt, Nt);
}

extern "C" void kernel_launch(void* const* d_in, const int* in_sizes, int n_in,
                              void* d_out, int out_size, void* d_ws, size_t ws_size,
                              hipStream_t stream)
{
    const float* params = (const float*)d_in[0];
    const float* p      = (const float*)d_in[1];
    const float* dpdt   = (const float*)d_in[2];
    const float* dtv    = (const float*)d_in[3];

    float* Rt = (float*)d_out;                       // B*(T+1)
    float* Nt = (float*)d_out + (size_t)B * (T + 1); // B*(T+1)

    crs_pair_kernel<<<B / 2, NTHR, 0, stream>>>(params, p, dpdt, dtv, Rt, Nt);
}

// Round 18
// 126.277 us; speedup vs baseline: 1.0388x; 1.0388x over previous
//
#include <hip/hip_runtime.h>

// CRS rate-and-state model. R -> et*R/(1+c*R) is a Mobius map [[a,0],[c,1]];
// maps compose associatively -> whole T=4096 row is ONE two-level scan.
// FINAL = R16 (best of 17 structures: 125.7us). R17's global_load_lds
// prefetch regressed (131us: LDS 67KB halved occupancy, 8-way stage-read
// bank conflicts 1.7M->9.0M > the ~15us read-leg overlap it bought).
// Structure: one 512-thread block per row, thread owns 8 contiguous steps.
//  phase 1: per-thread inclusive Mobius prefixes (A_j, C_j)
//  phase 2: 6-round wave shuffle-scan + cross-wave LDS composition
//  phase 3: closed-form outputs R_j = A_j*R~/(1+C_j*R~); N via log2
//           telescope n_j = (asig*rf*ln2)*(log2 L_j - log2 L_{j-1})
//  phase 4: two-level N prefix sum; R stores (VMEM) overlap N bounce (DS)
//  stores: dual skewed LDS bounce -> per-WAVE-INSTRUCTION lane-contiguous,
//          per-row phase shift -> 64B-aligned nt f4 stores.
// Wins on the way here: +RMW elimination via aligned stores (148->139),
// +nt stores for L3 input retention (139->128), 512-thr blocks (128->126).
// Dead ends (all counter-verified): occupancy 34->90% (no effect; not
// latency-starved), traffic -12% (time -1.5%; not BW-bound), register
// prefetch (compiler sinks it, 5 attempts), asm vmcnt pipelining (regalloc
// demotes the held regs), direct register stores (per-instruction lane
// sparsity = +3.2x/+12% WRITE amplification), LDS stage prefetch (R17).
// Model: ~75us memory leg (474MB @ ~4TB/s effective for this access mix)
// + ~50us VALU leg (2x exp/log/div per element + 2 scans), serialized by
// the scan's barrier structure -> ~126us. Matches 17/17 measurements.

#define C_TNSR  0.001f
#define C_TSSR  0.002f
#define C_SIGMA 50.0f
#define C_BIOT  0.3f
#define C_R0    0.0001f
#define C_N0    0.0001f
#define LN2F    0.69314718056f

constexpr int B = 8192;
constexpr int T = 4096;
constexpr int STEPS = 8;           // per thread
constexpr int NTHR  = 512;         // threads per block = one row
constexpr int WAVES = NTHR / 64;   // 8

typedef float f4 __attribute__((ext_vector_type(4)));

__device__ __forceinline__ int SIDX(int m) { return m + (m >> 5); }

// workgroup barrier WITHOUT the compiler's vmcnt(0) drain: LDS ordering only;
// draining would stall on our in-flight nt stores.
__device__ __forceinline__ void barrier_lgkm() {
    asm volatile("s_waitcnt lgkmcnt(0)\n\ts_barrier" ::: "memory");
}

__global__ __launch_bounds__(NTHR, 8)
void crs_row_kernel(const float* __restrict__ params,
                    const float* __restrict__ p,
                    const float* __restrict__ dpdt,
                    const float* __restrict__ dtv,
                    float* __restrict__ Rt,
                    float* __restrict__ Nt)
{
    __shared__ float lsR[T + T / 32];   // 16.5 KB, skew-indexed
    __shared__ float lsN[T + T / 32];
    __shared__ float sA[WAVES], sC[WAVES], sS[WAVES];

    const int tid  = threadIdx.x;
    const int lane = tid & 63;
    const int wid  = tid >> 6;
    const int b    = blockIdx.x;

    const float mu  = params[b * 3 + 0];
    const float rc  = params[b * 3 + 1];
    const float rf  = params[b * 3 + 2];
    const float eta = 1.0f / rf;
    const float rcS = rc * C_SIGMA;
    const float rcB = rc * C_BIOT;
    const float sdB = C_TSSR - mu * C_TNSR;    // sd = fma(mu, dpdt, sdB)
    const float rfln2 = rf * LN2F;             // kln = asig * rfln2

    const int seg = tid * STEPS;
    const float* __restrict__ prow = p    + (size_t)b * T + seg;
    const float* __restrict__ drow = dpdt + (size_t)b * T + seg;
    const float* __restrict__ trow = dtv  + (size_t)b * T + seg;

    // ---- load this thread's 8 steps (32B/thread dwordx4, dense) ----
    f4 pv0 = *(const f4*)(prow);
    f4 pv1 = *(const f4*)(prow + 4);
    f4 dv0 = *(const f4*)(drow);
    f4 dv1 = *(const f4*)(drow + 4);
    f4 tv0 = *(const f4*)(trow);
    f4 tv1 = *(const f4*)(trow + 4);

    // ---- phase 1: per-thread inclusive Mobius prefixes ----
    float Aj[STEPS], Cj[STEPS], kln[STEPS];
    float A = 1.0f, C = 0.0f;
#pragma unroll
    for (int j = 0; j < STEPS; ++j) {
        float pp = (j < 4) ? pv0[j] : pv1[j - 4];
        float dd = (j < 4) ? dv0[j] : dv1[j - 4];
        float tt = (j < 4) ? tv0[j] : tv1[j - 4];
        float sd   = fmaf(mu, dd, sdB);
        float asig = fmaf(-rcB, pp, rcS);
        float e    = __expf(__fdividef(sd * tt, asig));
        float c    = __fdividef(eta * (e - 1.0f), sd);
        kln[j] = asig * rfln2;           // (asig/eta)*ln2
        C = fmaf(c, A, C);               // compose step j after (A,C)
        A = A * e;
        Aj[j] = A;
        Cj[j] = C;
    }

    // ---- phase 2a: wave-inclusive scan of (A,C) ----
#pragma unroll
    for (int o = 1; o < 64; o <<= 1) {
        float Ap = __shfl_up(A, (unsigned)o, 64);
        float Cp = __shfl_up(C, (unsigned)o, 64);
        if (lane >= o) { C = fmaf(C, Ap, Cp); A = A * Ap; }
    }
    float Ae = __shfl_up(A, 1u, 64);
    float Ce = __shfl_up(C, 1u, 64);
    if (lane == 0) { Ae = 1.0f; Ce = 0.0f; }

    // ---- phase 2b: cross-wave composition via LDS ----
    if (lane == 63) { sA[wid] = A; sC[wid] = C; }
    barrier_lgkm();                                    // bar 1
    float PA = 1.0f, PC = 0.0f;
#pragma unroll
    for (int w = 0; w < WAVES - 1; ++w) {
        if (w < wid) { PC = fmaf(sC[w], PA, PC); PA = sA[w] * PA; }
    }
    float EA = Ae * PA;
    float EC = fmaf(Ce, PA, PC);
    float Rt_ = __fdividef(EA * C_R0, fmaf(EC, C_R0, 1.0f));   // R entering segment

    // ---- phase 3: closed-form outputs; N via log2 telescope ----
    // L_j = 1 + Cj*R~ ;  R_j = Aj*R~/L_j ;  n_j = kln_j*(lg_j - lg_{j-1}),
    // lg_j = log2(L_j), lg_{-1} = 0. All logs/rcps independent.
    float nn[STEPS];
    float ns = 0.0f;
    float lgPrev = 0.0f;
#pragma unroll
    for (int j = 0; j < STEPS; ++j) {
        float L   = fmaf(Cj[j], Rt_, 1.0f);
        float rlj = __fdividef(1.0f, L);
        lsR[SIDX(seg + j)] = (Aj[j] * Rt_) * rlj;
        float lg = __log2f(L);
        ns += kln[j] * (lg - lgPrev);
        nn[j] = ns;
        lgPrev = lg;
    }

    // ---- phase 4a: wave prefix sum of per-thread N totals (shuffles only) ----
    float S = ns;
#pragma unroll
    for (int o = 1; o < 64; o <<= 1) {
        float Sp = __shfl_up(S, (unsigned)o, 64);
        if (lane >= o) S += Sp;
    }
    if (lane == 63) sS[wid] = S;
    barrier_lgkm();                                    // bar 2: lsR + sS ready

    // ---- store-stage geometry ----
    const size_t g0 = (size_t)b * (T + 1) + 1;         // dword index of step 0
    const int s  = (int)((16 - (g0 & 15)) & 15);       // shift to 64B boundary
    const int tl = (T - s) & 3;                        // tail dwords
    const int bodyEnd = T - tl;

    // ---- R store stage FIRST (VMEM pipe; overlaps the N work below) ----
    if (tid == 0) {
        __builtin_nontemporal_store(C_R0, Rt + g0 - 1);
        __builtin_nontemporal_store(C_N0, Nt + g0 - 1);
    }
    if (tid < s)  __builtin_nontemporal_store(lsR[SIDX(tid)], Rt + g0 + tid);
    if (tid < tl) { int m = bodyEnd + tid;
                    __builtin_nontemporal_store(lsR[SIDX(m)], Rt + g0 + m); }
#pragma unroll
    for (int q = 0; q < 2; ++q) {                      // body: 64B-aligned f4
        int m0 = s + q * 2048 + tid * 4;
        if (m0 + 4 <= bodyEnd) {
            f4 r;
#pragma unroll
            for (int c = 0; c < 4; ++c) r[c] = lsR[SIDX(m0 + c)];
            __builtin_nontemporal_store(r, (f4*)(Rt + g0 + m0));
        }
    }

    // ---- phase 4b: cross-wave N base + bounce N (DS pipe, concurrent) ----
    float PS = C_N0;
#pragma unroll
    for (int w = 0; w < WAVES - 1; ++w) {
        if (w < wid) PS += sS[w];
    }
    float base = PS + (S - ns);
#pragma unroll
    for (int j = 0; j < STEPS; ++j)
        lsN[SIDX(seg + j)] = base + nn[j];

    barrier_lgkm();                                    // bar 3: N in LDS

    // ---- N store stage ----
    if (tid < s)  __builtin_nontemporal_store(lsN[SIDX(tid)], Nt + g0 + tid);
    if (tid < tl) { int m = bodyEnd + tid;
                    __builtin_nontemporal_store(lsN[SIDX(m)], Nt + g0 + m); }
#pragma unroll
    for (int q = 0; q < 2; ++q) {
        int m0 = s + q * 2048 + tid * 4;
        if (m0 + 4 <= bodyEnd) {
            f4 n;
#pragma unroll
            for (int c = 0; c < 4; ++c) n[c] = lsN[SIDX(m0 + c)];
            __builtin_nontemporal_store(n, (f4*)(Nt + g0 + m0));
        }
    }
}

extern "C" void kernel_launch(void* const* d_in, const int* in_sizes, int n_in,
                              void* d_out, int out_size, void* d_ws, size_t ws_size,
                              hipStream_t stream)
{
    const float* params = (const float*)d_in[0];
    const float* p      = (const float*)d_in[1];
    const float* dpdt   = (const float*)d_in[2];
    const float* dtv    = (const float*)d_in[3];

    float* Rt = (float*)d_out;                       // B*(T+1)
    float* Nt = (float*)d_out + (size_t)B * (T + 1); // B*(T+1)

    crs_row_kernel<<<B, NTHR, 0, stream>>>(params, p, dpdt, dtv, Rt, Nt);
}